// Round 1
// baseline (16283.022 us; speedup 1.0000x reference)
//
#include <hip/hip_runtime.h>
#include <cstddef>

#define LRATE 3e-4f

__device__ __forceinline__ float gelu_f(float x){
  float u = 0.7978845608028654f*(x + 0.044715f*x*x*x);
  float t = tanhf(u);
  return 0.5f*x*(1.f+t);
}
__device__ __forceinline__ float gelu_df(float x){
  float x2 = x*x;
  float u = 0.7978845608028654f*(x + 0.044715f*x*x2);
  float t = tanhf(u);
  return 0.5f*(1.f+t) + 0.5f*x*(1.f-t*t)*0.7978845608028654f*(1.f+0.134145f*x2);
}

// ---------------- GEMM NN: C[M,N] = A[M,K] @ B[K,N] (+bias, +resid, optional gelu(A), row remap)
__global__ __launch_bounds__(256) void k_gemm_nn(
    const float* __restrict__ Am, const float* __restrict__ Bm,
    const float* __restrict__ bias, const float* __restrict__ resid,
    float* __restrict__ C, int M, int N, int K, int geluA, int remap_c)
{
  __shared__ float As[16][66], Bs[16][66];
  int bm = blockIdx.y*64, bn = blockIdx.x*64;
  int tid = threadIdx.x;
  float acc[4][4] = {};
  for(int k0=0; k0<K; k0+=16){
    #pragma unroll
    for(int i=0;i<4;i++){
      int e = tid + i*256; int mm = e>>4, kk = e&15;
      float v = Am[(size_t)(bm+mm)*K + k0 + kk];
      if(geluA) v = gelu_f(v);
      As[kk][mm] = v;
    }
    #pragma unroll
    for(int i=0;i<4;i++){
      int e = tid + i*256; int kk = e>>6, nn = e&63;
      Bs[kk][nn] = Bm[(size_t)(k0+kk)*N + bn + nn];
    }
    __syncthreads();
    int ty = tid>>4, tx = tid&15;
    #pragma unroll
    for(int kk=0;kk<16;kk++){
      float a[4], b[4];
      #pragma unroll
      for(int i=0;i<4;i++) a[i] = As[kk][ty*4+i];
      #pragma unroll
      for(int j=0;j<4;j++) b[j] = Bs[kk][tx*4+j];
      #pragma unroll
      for(int i=0;i<4;i++)
        #pragma unroll
        for(int j=0;j<4;j++) acc[i][j] += a[i]*b[j];
    }
    __syncthreads();
  }
  int ty = tid>>4, tx = tid&15;
  #pragma unroll
  for(int i=0;i<4;i++){
    int m = bm + ty*4 + i;
    int mo = (remap_c>=0) ? ((m>>6)*256 + remap_c*64 + (m&63)) : m;
    #pragma unroll
    for(int j=0;j<4;j++){
      int n = bn + tx*4 + j;
      float v = acc[i][j];
      if(bias) v += bias[n];
      if(resid) v += resid[(size_t)m*N + n];
      C[(size_t)mo*N + n] = v;
    }
  }
}

// ---------------- GEMM NT: C[M,N] = A[M,K] @ B^T,  B stored [N,K]
__global__ __launch_bounds__(256) void k_gemm_nt(
    const float* __restrict__ Am, const float* __restrict__ Bm,
    float* __restrict__ C, int M, int N, int K)
{
  __shared__ float As[16][66], Bs[16][66];
  int bm = blockIdx.y*64, bn = blockIdx.x*64;
  int tid = threadIdx.x;
  float acc[4][4] = {};
  for(int k0=0; k0<K; k0+=16){
    #pragma unroll
    for(int i=0;i<4;i++){
      int e = tid + i*256; int mm = e>>4, kk = e&15;
      As[kk][mm] = Am[(size_t)(bm+mm)*K + k0 + kk];
    }
    #pragma unroll
    for(int i=0;i<4;i++){
      int e = tid + i*256; int nn = e>>4, kk = e&15;
      Bs[kk][nn] = Bm[(size_t)(bn+nn)*K + k0 + kk];
    }
    __syncthreads();
    int ty = tid>>4, tx = tid&15;
    #pragma unroll
    for(int kk=0;kk<16;kk++){
      float a[4], b[4];
      #pragma unroll
      for(int i=0;i<4;i++) a[i] = As[kk][ty*4+i];
      #pragma unroll
      for(int j=0;j<4;j++) b[j] = Bs[kk][tx*4+j];
      #pragma unroll
      for(int i=0;i<4;i++)
        #pragma unroll
        for(int j=0;j<4;j++) acc[i][j] += a[i]*b[j];
    }
    __syncthreads();
  }
  int ty = tid>>4, tx = tid&15;
  #pragma unroll
  for(int i=0;i<4;i++)
    #pragma unroll
    for(int j=0;j<4;j++)
      C[(size_t)(bm+ty*4+i)*N + bn+tx*4+j] = acc[i][j];
}

// ---------------- GEMM TN + SGD: W[M,N] -= LR * (A^T @ B), A stored [K=256,M], B [K=256,N]
__global__ __launch_bounds__(256) void k_gemm_tn_sgd(
    const float* __restrict__ Am, const float* __restrict__ Bm,
    float* __restrict__ W, int M, int N, int geluA)
{
  __shared__ float As[16][66], Bs[16][66];
  int bm = blockIdx.y*64, bn = blockIdx.x*64;
  int tid = threadIdx.x;
  float acc[4][4] = {};
  for(int k0=0; k0<256; k0+=16){
    #pragma unroll
    for(int i=0;i<4;i++){
      int e = tid + i*256; int kk = e>>6, mm = e&63;
      float v = Am[(size_t)(k0+kk)*M + bm + mm];
      if(geluA) v = gelu_f(v);
      As[kk][mm] = v;
    }
    #pragma unroll
    for(int i=0;i<4;i++){
      int e = tid + i*256; int kk = e>>6, nn = e&63;
      Bs[kk][nn] = Bm[(size_t)(k0+kk)*N + bn + nn];
    }
    __syncthreads();
    int ty = tid>>4, tx = tid&15;
    #pragma unroll
    for(int kk=0;kk<16;kk++){
      float a[4], b[4];
      #pragma unroll
      for(int i=0;i<4;i++) a[i] = As[kk][ty*4+i];
      #pragma unroll
      for(int j=0;j<4;j++) b[j] = Bs[kk][tx*4+j];
      #pragma unroll
      for(int i=0;i<4;i++)
        #pragma unroll
        for(int j=0;j<4;j++) acc[i][j] += a[i]*b[j];
    }
    __syncthreads();
  }
  int ty = tid>>4, tx = tid&15;
  #pragma unroll
  for(int i=0;i<4;i++)
    #pragma unroll
    for(int j=0;j<4;j++)
      W[(size_t)(bm+ty*4+i)*N + bn+tx*4+j] -= LRATE*acc[i][j];
}

// ---------------- dhf = dlogits @ head_w^T, dlogits computed on-the-fly. Split-K 16.
// M=256, N=512, K=32000; Cpart[z][256][512]
__global__ __launch_bounds__(256) void k_gemm_dhf(
    const float* __restrict__ logits, const float* __restrict__ hw, const int* __restrict__ x,
    const float* __restrict__ rowm, const float* __restrict__ rowiz,
    float* __restrict__ Cpart, int chunk)
{
  __shared__ float As[16][66], Bs[16][66];
  __shared__ int tgtL[64];
  __shared__ float mL[64], izL[64];
  int bn = blockIdx.x*64, bm = blockIdx.y*64, z = blockIdx.z;
  int tid = threadIdx.x;
  if(tid < 64){
    int m = bm + tid; int b = m>>6, t = m&63;
    tgtL[tid] = x[b*257 + chunk*64 + t + 1];
    mL[tid] = rowm[m];
    izL[tid] = rowiz[m]*(1.f/256.f);
  }
  __syncthreads();
  float acc[4][4] = {};
  for(int k0 = z*2000; k0 < (z+1)*2000; k0+=16){
    #pragma unroll
    for(int i=0;i<4;i++){
      int e = tid + i*256; int mm = e>>4, kk = e&15;
      int m = bm + mm; int v = k0 + kk;
      int R = (m>>6)*256 + chunk*64 + (m&63);
      float l = logits[(size_t)R*32000 + v];
      float a = expf(l - mL[mm]) * izL[mm];
      if(v == tgtL[mm]) a -= (1.f/256.f);
      As[kk][mm] = a;
    }
    #pragma unroll
    for(int i=0;i<4;i++){
      int e = tid + i*256; int nn = e>>4, kk = e&15;
      Bs[kk][nn] = hw[(size_t)(bn+nn)*32000 + k0 + kk];
    }
    __syncthreads();
    int ty = tid>>4, tx = tid&15;
    #pragma unroll
    for(int kk=0;kk<16;kk++){
      float a[4], b[4];
      #pragma unroll
      for(int i=0;i<4;i++) a[i] = As[kk][ty*4+i];
      #pragma unroll
      for(int j=0;j<4;j++) b[j] = Bs[kk][tx*4+j];
      #pragma unroll
      for(int i=0;i<4;i++)
        #pragma unroll
        for(int j=0;j<4;j++) acc[i][j] += a[i]*b[j];
    }
    __syncthreads();
  }
  int ty = tid>>4, tx = tid&15;
  #pragma unroll
  for(int i=0;i<4;i++)
    #pragma unroll
    for(int j=0;j<4;j++)
      Cpart[(size_t)z*131072 + (size_t)(bm+ty*4+i)*512 + bn+tx*4+j] = acc[i][j];
}

__global__ __launch_bounds__(256) void k_reduce16(const float* __restrict__ p, float* __restrict__ o){
  int i = blockIdx.x*256 + threadIdx.x;
  float s = 0;
  #pragma unroll
  for(int z=0;z<16;z++) s += p[(size_t)z*131072 + i];
  o[i] = s;
}

// ---------------- embed + pos
__global__ __launch_bounds__(256) void k_embed(const int* __restrict__ x, const float* __restrict__ emb,
    const float* __restrict__ pos, float* __restrict__ h, int chunk)
{
  int n = blockIdx.x, tid = threadIdx.x;
  int b = n>>6, t = n&63;
  int tok = x[b*257 + chunk*64 + t];
  size_t b0 = (size_t)n*512 + tid;
  h[b0]     = emb[(size_t)tok*512 + tid]       + pos[t*512 + tid];
  h[b0+256] = emb[(size_t)tok*512 + tid + 256] + pos[t*512 + tid + 256];
}

// ---------------- LayerNorm fwd (saves mean, rstd)
__global__ __launch_bounds__(256) void k_ln_fwd(const float* __restrict__ x, const float* __restrict__ g,
    const float* __restrict__ b, float* __restrict__ y, float* __restrict__ mean, float* __restrict__ rstd)
{
  int n = blockIdx.x, tid = threadIdx.x;
  size_t b0 = (size_t)n*512 + tid;
  float x0 = x[b0], x1 = x[b0+256];
  __shared__ float red[256];
  red[tid] = x0 + x1; __syncthreads();
  for(int o=128;o;o>>=1){ if(tid<o) red[tid]+=red[tid+o]; __syncthreads(); }
  float m = red[0]*(1.f/512.f); __syncthreads();
  float d0 = x0-m, d1 = x1-m;
  red[tid] = d0*d0 + d1*d1; __syncthreads();
  for(int o=128;o;o>>=1){ if(tid<o) red[tid]+=red[tid+o]; __syncthreads(); }
  float r = rsqrtf(red[0]*(1.f/512.f) + 1e-5f);
  if(tid==0){ mean[n]=m; rstd[n]=r; }
  y[b0]     = d0*r*g[tid]     + b[tid];
  y[b0+256] = d1*r*g[tid+256] + b[tid+256];
}

// ---------------- LayerNorm bwd (dx = addin + ln_bwd(dy))
__global__ __launch_bounds__(256) void k_ln_bwd(const float* __restrict__ dy, const float* __restrict__ x,
    const float* __restrict__ g, const float* __restrict__ mean, const float* __restrict__ rstd,
    const float* __restrict__ addin, float* __restrict__ dx)
{
  int n = blockIdx.x, tid = threadIdx.x;
  float m = mean[n], r = rstd[n];
  size_t b0 = (size_t)n*512 + tid;
  float x0 = x[b0], x1 = x[b0+256];
  float xh0 = (x0-m)*r, xh1 = (x1-m)*r;
  float gh0 = dy[b0]*g[tid], gh1 = dy[b0+256]*g[tid+256];
  __shared__ float r1[256], r2[256];
  r1[tid] = gh0+gh1; r2[tid] = gh0*xh0 + gh1*xh1;
  __syncthreads();
  for(int o=128;o;o>>=1){ if(tid<o){ r1[tid]+=r1[tid+o]; r2[tid]+=r2[tid+o]; } __syncthreads(); }
  float mg = r1[0]*(1.f/512.f), mgx = r2[0]*(1.f/512.f);
  float d0 = (gh0 - mg - xh0*mgx)*r;
  float d1 = (gh1 - mg - xh1*mgx)*r;
  if(addin){ d0 += addin[b0]; d1 += addin[b0+256]; }
  dx[b0] = d0; dx[b0+256] = d1;
}

// ---------------- attention forward (per (qtile,head,batch)); saves probs
__global__ __launch_bounds__(256) void k_attn_fwd(const float* __restrict__ qkv, float* __restrict__ o,
    float* __restrict__ ap)
{
  int qt = blockIdx.x, hh = blockIdx.y, bb = blockIdx.z;
  __shared__ float Ks[64][65], Vs[64][65], Qs[16][65], Ps[16][64];
  int tid = threadIdx.x;
  for(int e=tid;e<4096;e+=256){
    int j=e>>6, d=e&63;
    size_t base = (size_t)(bb*64+j)*1536 + hh*64 + d;
    Ks[j][d] = qkv[base + 512];
    Vs[j][d] = qkv[base + 1024];
  }
  for(int e=tid;e<1024;e+=256){
    int i=e>>6, d=e&63;
    Qs[i][d] = qkv[(size_t)(bb*64+qt*16+i)*1536 + hh*64 + d];
  }
  __syncthreads();
  int lane = tid&63, w = tid>>6;
  #pragma unroll
  for(int e=0;e<4;e++){
    int i = w + e*4, j = lane;
    int qi = qt*16 + i;
    float s2 = 0;
    #pragma unroll
    for(int d=0; d<64; d++) s2 += Qs[i][d]*Ks[j][d];
    float sval = (j<=qi) ? s2*0.125f : -1e9f;
    float mx = sval;
    #pragma unroll
    for(int off=32;off;off>>=1) mx = fmaxf(mx, __shfl_xor(mx,off));
    float ex = expf(sval - mx);
    float sm = ex;
    #pragma unroll
    for(int off=32;off;off>>=1) sm += __shfl_xor(sm,off);
    float p = ex/sm;
    Ps[i][j] = p;
    ap[(size_t)((bb*8+hh)*64 + qi)*64 + j] = p;
  }
  __syncthreads();
  #pragma unroll
  for(int e=0;e<4;e++){
    int i = w + e*4, d = lane;
    float acc = 0;
    #pragma unroll
    for(int j=0;j<64;j++) acc += Ps[i][j]*Vs[j][d];
    o[(size_t)(bb*64+qt*16+i)*512 + hh*64 + d] = acc;
  }
}

// ---------------- attention backward, q-side: ds (saved) and dq
__global__ __launch_bounds__(256) void k_attn_bwd_q(const float* __restrict__ qkv, const float* __restrict__ dob,
    const float* __restrict__ ap, float* __restrict__ dsb, float* __restrict__ dqkv)
{
  int qt = blockIdx.x, hh = blockIdx.y, bb = blockIdx.z;
  __shared__ float Ks[64][65], Vs[64][65], DOs[16][65], Ss[16][64], Aps[16][64];
  int tid = threadIdx.x;
  for(int e=tid;e<4096;e+=256){
    int j=e>>6, d=e&63;
    size_t base = (size_t)(bb*64+j)*1536 + hh*64 + d;
    Ks[j][d] = qkv[base + 512];
    Vs[j][d] = qkv[base + 1024];
  }
  for(int e=tid;e<1024;e+=256){
    int i=e>>6, d=e&63;
    DOs[i][d] = dob[(size_t)(bb*64+qt*16+i)*512 + hh*64 + d];
    Aps[i][d] = ap[(size_t)((bb*8+hh)*64 + qt*16+i)*64 + d];
  }
  __syncthreads();
  int lane = tid&63, w = tid>>6;
  #pragma unroll
  for(int e=0;e<4;e++){
    int i = w + e*4, j = lane;
    float da = 0;
    #pragma unroll
    for(int d=0;d<64;d++) da += DOs[i][d]*Vs[j][d];
    float a = Aps[i][j];
    float r = da*a;
    #pragma unroll
    for(int off=32;off;off>>=1) r += __shfl_xor(r,off);
    float ds = a*(da - r)*0.125f;
    Ss[i][j] = ds;
    dsb[(size_t)((bb*8+hh)*64 + qt*16+i)*64 + j] = ds;
  }
  __syncthreads();
  #pragma unroll
  for(int e=0;e<4;e++){
    int i = w + e*4, d = lane;
    float acc = 0;
    #pragma unroll
    for(int j=0;j<64;j++) acc += Ss[i][j]*Ks[j][d];
    dqkv[(size_t)(bb*64+qt*16+i)*1536 + hh*64 + d] = acc;
  }
}

// ---------------- attention backward, kv-side: dk, dv
__global__ __launch_bounds__(256) void k_attn_bwd_kv(const float* __restrict__ qkv, const float* __restrict__ dob,
    const float* __restrict__ ap, const float* __restrict__ dsb, float* __restrict__ dqkv)
{
  int kt = blockIdx.x, hh = blockIdx.y, bb = blockIdx.z;
  __shared__ float Qs[64][65], DOs[64][65], DSt[64][17], At[64][17];
  int tid = threadIdx.x;
  for(int e=tid;e<4096;e+=256){
    int i=e>>6, d=e&63;
    Qs[i][d]  = qkv[(size_t)(bb*64+i)*1536 + hh*64 + d];
    DOs[i][d] = dob[(size_t)(bb*64+i)*512 + hh*64 + d];
  }
  for(int e=tid;e<1024;e+=256){
    int i=e>>4, jj=e&15;
    size_t idx = (size_t)((bb*8+hh)*64 + i)*64 + kt*16 + jj;
    DSt[i][jj] = dsb[idx];
    At[i][jj]  = ap[idx];
  }
  __syncthreads();
  int lane = tid&63, w = tid>>6;
  #pragma unroll
  for(int e=0;e<4;e++){
    int jj = w + e*4, d = lane;
    float dk = 0, dv = 0;
    #pragma unroll
    for(int i2=0;i2<64;i2++){
      dk += DSt[i2][jj]*Qs[i2][d];
      dv += At[i2][jj]*DOs[i2][d];
    }
    size_t row = (size_t)(bb*64 + kt*16 + jj)*1536 + hh*64 + d;
    dqkv[row + 512]  = dk;
    dqkv[row + 1024] = dv;
  }
}

// ---------------- CE stats: per-row max and 1/sumexp over 32000
__global__ __launch_bounds__(256) void k_ce_stats(const float* __restrict__ out,
    float* __restrict__ rowm, float* __restrict__ rowiz, int chunk)
{
  int n = blockIdx.x, tid = threadIdx.x;
  int R = (n>>6)*256 + chunk*64 + (n&63);
  const float* row = out + (size_t)R*32000;
  __shared__ float red[256];
  float mx = -3.4e38f;
  for(int v=tid; v<32000; v+=256) mx = fmaxf(mx, row[v]);
  red[tid] = mx; __syncthreads();
  for(int o=128;o;o>>=1){ if(tid<o) red[tid]=fmaxf(red[tid],red[tid+o]); __syncthreads(); }
  float m = red[0]; __syncthreads();
  float s = 0;
  for(int v=tid; v<32000; v+=256) s += expf(row[v]-m);
  red[tid] = s; __syncthreads();
  for(int o=128;o;o>>=1){ if(tid<o) red[tid]+=red[tid+o]; __syncthreads(); }
  if(tid==0){ rowm[n]=m; rowiz[n]=1.f/red[0]; }
}

// ---------------- elementwise
__global__ __launch_bounds__(256) void k_gelu_bwd(float* __restrict__ dg, const float* __restrict__ z){
  int i = blockIdx.x*256 + threadIdx.x;
  dg[i] *= gelu_df(z[i]);
}

__global__ __launch_bounds__(256) void k_colsum_sgd(const float* __restrict__ X, float* __restrict__ bv, int N){
  int c = blockIdx.x*256 + threadIdx.x;
  if(c < N){
    float s = 0;
    for(int n=0;n<256;n++) s += X[(size_t)n*N + c];
    bv[c] -= LRATE*s;
  }
}

extern "C" void kernel_launch(void* const* d_in, const int* in_sizes, int n_in,
                              void* d_out, int out_size, void* d_ws, size_t ws_size,
                              hipStream_t stream)
{
  const int*   x      = (const int*)d_in[0];
  const float* embed  = (const float*)d_in[1];
  const float* pos    = (const float*)d_in[2];
  const float* ln1_g  = (const float*)d_in[3];
  const float* ln1_b  = (const float*)d_in[4];
  const float* qkv_w  = (const float*)d_in[5];
  const float* qkv_b  = (const float*)d_in[6];
  const float* proj_w = (const float*)d_in[7];
  const float* proj_b = (const float*)d_in[8];
  const float* ln2_g  = (const float*)d_in[9];
  const float* ln2_b  = (const float*)d_in[10];
  const float* mlp_w1 = (const float*)d_in[11];
  const float* mlp_b1 = (const float*)d_in[12];
  const float* mlp_w2 = (const float*)d_in[13];
  const float* mlp_b2 = (const float*)d_in[14];
  const float* lnf_g  = (const float*)d_in[15];
  const float* lnf_b  = (const float*)d_in[16];
  const float* head_w = (const float*)d_in[17];
  const float* head_b = (const float*)d_in[18];
  float* out = (float*)d_out;
  float* ws  = (float*)d_ws;

  size_t off = 0;
  auto A = [&](size_t n){ float* p = ws + off; off += n; return p; };
  float* W1c  = A(4194304); float* B1c = A(8192);
  float* W2c  = A(4194304); float* B2c = A(2048);
  float* hin  = A(5*131072);          // h checkpoints (input of each block + final)
  float* h1s  = A(4*131072);          // h after attn residual
  float* xn2s = A(4*131072);          // LN2 outputs
  float* qkvs = A(4*393216);
  float* aps  = A(4*131072);          // attn probs
  float* z1s  = A(4*524288);          // pre-gelu mlp1
  float* xn1  = A(131072);
  float* hfb  = A(131072);
  float* obuf = A(131072);
  float* dsb  = A(131072);
  float* ln1m = A(1024); float* ln1r = A(1024);
  float* ln2m = A(1024); float* ln2r = A(1024);
  float* lnfm = A(256);  float* lnfr = A(256);
  float* rowm = A(256);  float* rowiz = A(256);
  float* dpart = A(16*131072);
  float* dhfb = A(131072);
  float* dhA  = A(131072); float* dhB = A(131072);
  float* dg1  = A(524288);
  float* dxn  = A(131072);
  float* dob  = A(131072);
  float* dqkv = A(393216);

  // fresh copy of MLP params each call (they are SGD-updated in place)
  hipMemcpyAsync(W1c, mlp_w1, 4194304*sizeof(float), hipMemcpyDeviceToDevice, stream);
  hipMemcpyAsync(B1c, mlp_b1, 8192*sizeof(float),    hipMemcpyDeviceToDevice, stream);
  hipMemcpyAsync(W2c, mlp_w2, 4194304*sizeof(float), hipMemcpyDeviceToDevice, stream);
  hipMemcpyAsync(B2c, mlp_b2, 2048*sizeof(float),    hipMemcpyDeviceToDevice, stream);

  for(int c=0;c<4;c++){
    // ---- forward ----
    k_embed<<<256,256,0,stream>>>(x, embed, pos, hin, c);
    for(int i=0;i<4;i++){
      float* h0 = hin + (size_t)i*131072;
      float* h2 = hin + (size_t)(i+1)*131072;
      float* h1 = h1s + (size_t)i*131072;
      float* xn2 = xn2s + (size_t)i*131072;
      float* qk = qkvs + (size_t)i*393216;
      float* ap = aps + (size_t)i*131072;
      float* z1 = z1s + (size_t)i*524288;
      k_ln_fwd<<<256,256,0,stream>>>(h0, ln1_g+i*512, ln1_b+i*512, xn1, ln1m+i*256, ln1r+i*256);
      k_gemm_nn<<<dim3(24,4),256,0,stream>>>(xn1, qkv_w+(size_t)i*786432, qkv_b+i*1536, nullptr, qk, 256,1536,512, 0, -1);
      k_attn_fwd<<<dim3(4,8,4),256,0,stream>>>(qk, obuf, ap);
      k_gemm_nn<<<dim3(8,4),256,0,stream>>>(obuf, proj_w+(size_t)i*262144, proj_b+i*512, h0, h1, 256,512,512, 0, -1);
      k_ln_fwd<<<256,256,0,stream>>>(h1, ln2_g+i*512, ln2_b+i*512, xn2, ln2m+i*256, ln2r+i*256);
      k_gemm_nn<<<dim3(32,4),256,0,stream>>>(xn2, W1c+(size_t)i*1048576, B1c+i*2048, nullptr, z1, 256,2048,512, 0, -1);
      k_gemm_nn<<<dim3(8,4),256,0,stream>>>(z1, W2c+(size_t)i*1048576, B2c+i*512, h1, h2, 256,512,2048, 1, -1);
    }
    k_ln_fwd<<<256,256,0,stream>>>(hin+4*131072, lnf_g, lnf_b, hfb, lnfm, lnfr);
    k_gemm_nn<<<dim3(500,4),256,0,stream>>>(hfb, head_w, head_b, nullptr, out, 256,32000,512, 0, c);

    // ---- backward ----
    k_ce_stats<<<256,256,0,stream>>>(out, rowm, rowiz, c);
    k_gemm_dhf<<<dim3(8,4,16),256,0,stream>>>(out, head_w, x, rowm, rowiz, dpart, c);
    k_reduce16<<<512,256,0,stream>>>(dpart, dhfb);
    k_ln_bwd<<<256,256,0,stream>>>(dhfb, hin+4*131072, lnf_g, lnfm, lnfr, nullptr, dhA);
    for(int i=3;i>=0;i--){
      float* h0 = hin + (size_t)i*131072;
      float* h1 = h1s + (size_t)i*131072;
      float* xn2 = xn2s + (size_t)i*131072;
      float* qk = qkvs + (size_t)i*393216;
      float* ap = aps + (size_t)i*131072;
      float* z1 = z1s + (size_t)i*524288;
      // MLP backward (dhA = dh2)
      k_gemm_nt<<<dim3(32,4),256,0,stream>>>(dhA, W2c+(size_t)i*1048576, dg1, 256,2048,512);   // dg1 (reads W2)
      k_colsum_sgd<<<2,256,0,stream>>>(dhA, B2c+i*512, 512);                                   // b2 update
      k_gemm_tn_sgd<<<dim3(8,32),256,0,stream>>>(z1, dhA, W2c+(size_t)i*1048576, 2048,512, 1); // W2 -= LR*gelu(z1)^T dh2
      k_gelu_bwd<<<2048,256,0,stream>>>(dg1, z1);                                              // dg1 -> dz1
      k_gemm_nt<<<dim3(8,4),256,0,stream>>>(dg1, W1c+(size_t)i*1048576, dxn, 256,512,2048);    // dxn2 (reads W1)
      k_colsum_sgd<<<8,256,0,stream>>>(dg1, B1c+i*2048, 2048);                                 // b1 update
      k_gemm_tn_sgd<<<dim3(32,8),256,0,stream>>>(xn2, dg1, W1c+(size_t)i*1048576, 512,2048, 0);// W1 update
      k_ln_bwd<<<256,256,0,stream>>>(dxn, h1, ln2_g+i*512, ln2m+i*256, ln2r+i*256, dhA, dhB);  // dh1
      // attention backward
      k_gemm_nt<<<dim3(8,4),256,0,stream>>>(dhB, proj_w+(size_t)i*262144, dob, 256,512,512);   // do
      k_attn_bwd_q<<<dim3(4,8,4),256,0,stream>>>(qk, dob, ap, dsb, dqkv);
      k_attn_bwd_kv<<<dim3(4,8,4),256,0,stream>>>(qk, dob, ap, dsb, dqkv);
      k_gemm_nt<<<dim3(8,4),256,0,stream>>>(dqkv, qkv_w+(size_t)i*786432, dxn, 256,512,1536);  // dxn1
      k_ln_bwd<<<256,256,0,stream>>>(dxn, h0, ln1_g+i*512, ln1m+i*256, ln1r+i*256, dhB, dhA);  // dh0
    }
  }
}

// Round 2
// 4979.990 us; speedup vs baseline: 3.2697x; 3.2697x over previous
//
#include <hip/hip_runtime.h>
#include <cstddef>

#define LRATE 3e-4f

typedef short short8 __attribute__((ext_vector_type(8)));
typedef float f32x4 __attribute__((ext_vector_type(4)));
typedef __bf16 bf16x8 __attribute__((ext_vector_type(8)));
typedef unsigned short ushort4v __attribute__((ext_vector_type(4)));

__device__ __forceinline__ unsigned short f2b(float f){
  unsigned u = __builtin_bit_cast(unsigned, f);
  unsigned r = (u + 0x7fffu + ((u>>16)&1u)) >> 16;
  return (unsigned short)r;
}
__device__ __forceinline__ float b2f(unsigned short s){
  unsigned u = ((unsigned)s)<<16;
  return __builtin_bit_cast(float, u);
}

__device__ __forceinline__ float gelu_f(float x){
  float u = 0.7978845608028654f*(x + 0.044715f*x*x*x);
  float t = tanhf(u);
  return 0.5f*x*(1.f+t);
}
__device__ __forceinline__ float gelu_df(float x){
  float x2 = x*x;
  float u = 0.7978845608028654f*(x + 0.044715f*x*x2);
  float t = tanhf(u);
  return 0.5f*(1.f+t) + 0.5f*x*(1.f-t*t)*0.7978845608028654f*(1.f+0.134145f*x2);
}

// ============ universal bf16 MFMA GEMM ============
// TA=0: A[M,K] row-major. TA=1: A[K,M] (TN, K-major) — C=A^T B.
// TB=0: B[K,N] row-major (NN). TB=1: B[N,K] (NT: C=A B^T).
// EPI=0: C -> (bias?, resid?) -> outf fp32 (+split-K z offset, row remap) ; outb bf16 (opt gelu)
// EPI=1: W[m,n] -= LR*C ; write fp32 master Wf and bf16 copy Wb
template<int TA, int TB, int EPI>
__global__ __launch_bounds__(256) void k_mm(
    const unsigned short* __restrict__ Ag, const unsigned short* __restrict__ Bg,
    const float* __restrict__ bias, const float* __restrict__ resid,
    float* __restrict__ outf, unsigned short* __restrict__ outb,
    float* __restrict__ Wf, unsigned short* __restrict__ Wb,
    int M, int N, int K, int k_iters, int gelu_b, int remap_c)
{
  __shared__ short Asm[64*40];
  __shared__ short Bsm[64*40];
  int tid = threadIdx.x;
  int bm = blockIdx.y*64, bn = blockIdx.x*64;
  int k0 = blockIdx.z * k_iters * 32;
  f32x4 acc00={},acc01={},acc10={},acc11={};
  int lane = tid&63, w = tid>>6, wr = w>>1, wc = w&1;
  int r16 = lane&15, kg = lane>>4;

  for(int it=0; it<k_iters; ++it, k0+=32){
    if(TA==0){
      int mm = tid>>2, ksb = tid&3;           // k-block 0..3
      short8 v = *(const short8*)(Ag + (size_t)(bm+mm)*K + k0 + ksb*8);
      int pos = ksb ^ ((mm>>3)&3);
      *(short8*)(Asm + mm*40 + pos*8) = v;
    } else {
      int kk = tid>>3, ms = (tid&7)*8;
      short8 v = *(const short8*)(Ag + (size_t)(k0+kk)*M + bm + ms);
      #pragma unroll
      for(int j=0;j<8;j++){
        int row = ms+j;
        Asm[row*40 + (((kk>>3) ^ ((row>>3)&3))<<3) + (kk&7)] = v[j];
      }
    }
    if(TB==0){
      int kk = tid>>3, ns = (tid&7)*8;
      short8 v = *(const short8*)(Bg + (size_t)(k0+kk)*N + bn + ns);
      #pragma unroll
      for(int j=0;j<8;j++){
        int row = ns+j;
        Bsm[row*40 + (((kk>>3) ^ ((row>>3)&3))<<3) + (kk&7)] = v[j];
      }
    } else {
      int nn = tid>>2, ksb = tid&3;
      short8 v = *(const short8*)(Bg + (size_t)(bn+nn)*K + k0 + ksb*8);
      int pos = ksb ^ ((nn>>3)&3);
      *(short8*)(Bsm + nn*40 + pos*8) = v;
    }
    __syncthreads();
    int ra0 = wr*32 + r16,      ra1 = wr*32 + 16 + r16;
    int rb0 = wc*32 + r16,      rb1 = wc*32 + 16 + r16;
    bf16x8 a0 = __builtin_bit_cast(bf16x8, *(const short8*)(Asm + ra0*40 + ((kg ^ ((ra0>>3)&3))<<3)));
    bf16x8 a1 = __builtin_bit_cast(bf16x8, *(const short8*)(Asm + ra1*40 + ((kg ^ ((ra1>>3)&3))<<3)));
    bf16x8 b0 = __builtin_bit_cast(bf16x8, *(const short8*)(Bsm + rb0*40 + ((kg ^ ((rb0>>3)&3))<<3)));
    bf16x8 b1 = __builtin_bit_cast(bf16x8, *(const short8*)(Bsm + rb1*40 + ((kg ^ ((rb1>>3)&3))<<3)));
    acc00 = __builtin_amdgcn_mfma_f32_16x16x32_bf16(a0, b0, acc00, 0,0,0);
    acc01 = __builtin_amdgcn_mfma_f32_16x16x32_bf16(a0, b1, acc01, 0,0,0);
    acc10 = __builtin_amdgcn_mfma_f32_16x16x32_bf16(a1, b0, acc10, 0,0,0);
    acc11 = __builtin_amdgcn_mfma_f32_16x16x32_bf16(a1, b1, acc11, 0,0,0);
    __syncthreads();
  }

  int rb = lane>>4;
  #pragma unroll
  for(int ar=0;ar<2;ar++){
    #pragma unroll
    for(int bc=0;bc<2;bc++){
      f32x4 av = (ar==0) ? (bc==0?acc00:acc01) : (bc==0?acc10:acc11);
      #pragma unroll
      for(int i=0;i<4;i++){
        int m = bm + wr*32 + ar*16 + rb*4 + i;
        int n = bn + wc*32 + bc*16 + r16;
        float v = av[i];
        if constexpr (EPI==0){
          if(bias) v += bias[n];
          if(resid) v += resid[(size_t)m*N + n];
          int mo = (remap_c>=0)? ((m>>6)*256 + remap_c*64 + (m&63)) : m;
          if(outf) outf[(size_t)blockIdx.z*M*N + (size_t)mo*N + n] = v;
          if(outb) outb[(size_t)mo*N + n] = f2b(gelu_b ? gelu_f(v) : v);
        } else {
          size_t oi = (size_t)m*N + n;
          float wv = Wf[oi] - LRATE*v;
          Wf[oi] = wv;
          Wb[oi] = f2b(wv);
        }
      }
    }
  }
}

// ============ converts ============
__global__ __launch_bounds__(256) void k_cvt(const float* __restrict__ s, unsigned short* __restrict__ d, int n){
  int i = (blockIdx.x*256 + threadIdx.x)*4;
  if(i < n){
    float4 v = *(const float4*)(s+i);
    ushort4v o; o.x=f2b(v.x); o.y=f2b(v.y); o.z=f2b(v.z); o.w=f2b(v.w);
    *(ushort4v*)(d+i) = o;
  }
}
__global__ __launch_bounds__(256) void k_cvt_dual(const float* __restrict__ s, float* __restrict__ df,
    unsigned short* __restrict__ db, int n){
  int i = (blockIdx.x*256 + threadIdx.x)*4;
  if(i < n){
    float4 v = *(const float4*)(s+i);
    *(float4*)(df+i) = v;
    ushort4v o; o.x=f2b(v.x); o.y=f2b(v.y); o.z=f2b(v.z); o.w=f2b(v.w);
    *(ushort4v*)(db+i) = o;
  }
}

// ============ embed + pos ============
__global__ __launch_bounds__(256) void k_embed(const int* __restrict__ x, const float* __restrict__ emb,
    const float* __restrict__ pos, float* __restrict__ h, int chunk)
{
  int n = blockIdx.x, tid = threadIdx.x;
  int b = n>>6, t = n&63;
  int tok = x[b*257 + chunk*64 + t];
  size_t b0 = (size_t)n*512 + tid;
  h[b0]     = emb[(size_t)tok*512 + tid]       + pos[t*512 + tid];
  h[b0+256] = emb[(size_t)tok*512 + tid + 256] + pos[t*512 + tid + 256];
}

// ============ LayerNorm fwd -> bf16 y ============
__global__ __launch_bounds__(256) void k_ln_fwd(const float* __restrict__ x, const float* __restrict__ g,
    const float* __restrict__ b, unsigned short* __restrict__ yb, float* __restrict__ mean, float* __restrict__ rstd)
{
  int n = blockIdx.x, tid = threadIdx.x;
  size_t b0 = (size_t)n*512 + tid;
  float x0 = x[b0], x1 = x[b0+256];
  __shared__ float red[256];
  red[tid] = x0 + x1; __syncthreads();
  for(int o=128;o;o>>=1){ if(tid<o) red[tid]+=red[tid+o]; __syncthreads(); }
  float m = red[0]*(1.f/512.f); __syncthreads();
  float d0 = x0-m, d1 = x1-m;
  red[tid] = d0*d0 + d1*d1; __syncthreads();
  for(int o=128;o;o>>=1){ if(tid<o) red[tid]+=red[tid+o]; __syncthreads(); }
  float r = rsqrtf(red[0]*(1.f/512.f) + 1e-5f);
  if(tid==0){ mean[n]=m; rstd[n]=r; }
  yb[b0]     = f2b(d0*r*g[tid]     + b[tid]);
  yb[b0+256] = f2b(d1*r*g[tid+256] + b[tid+256]);
}

// ============ LayerNorm bwd: dx = addin + ln_bwd(dy); fp32 + bf16 out ============
__global__ __launch_bounds__(256) void k_ln_bwd(const float* __restrict__ dy, const float* __restrict__ x,
    const float* __restrict__ g, const float* __restrict__ mean, const float* __restrict__ rstd,
    const float* __restrict__ addin, float* __restrict__ dx, unsigned short* __restrict__ dxb)
{
  int n = blockIdx.x, tid = threadIdx.x;
  float m = mean[n], r = rstd[n];
  size_t b0 = (size_t)n*512 + tid;
  float x0 = x[b0], x1 = x[b0+256];
  float xh0 = (x0-m)*r, xh1 = (x1-m)*r;
  float gh0 = dy[b0]*g[tid], gh1 = dy[b0+256]*g[tid+256];
  __shared__ float r1[256], r2[256];
  r1[tid] = gh0+gh1; r2[tid] = gh0*xh0 + gh1*xh1;
  __syncthreads();
  for(int o=128;o;o>>=1){ if(tid<o){ r1[tid]+=r1[tid+o]; r2[tid]+=r2[tid+o]; } __syncthreads(); }
  float mg = r1[0]*(1.f/512.f), mgx = r2[0]*(1.f/512.f);
  float d0 = (gh0 - mg - xh0*mgx)*r;
  float d1 = (gh1 - mg - xh1*mgx)*r;
  if(addin){ d0 += addin[b0]; d1 += addin[b0+256]; }
  dx[b0] = d0; dx[b0+256] = d1;
  dxb[b0] = f2b(d0); dxb[b0+256] = f2b(d1);
}

// ============ attention forward ============
__global__ __launch_bounds__(256) void k_attn_fwd(const float* __restrict__ qkv, unsigned short* __restrict__ o,
    float* __restrict__ ap)
{
  int qt = blockIdx.x, hh = blockIdx.y, bb = blockIdx.z;
  __shared__ float Ks[64][65], Vs[64][65], Qs[16][65], Ps[16][64];
  int tid = threadIdx.x;
  for(int e=tid;e<4096;e+=256){
    int j=e>>6, d=e&63;
    size_t base = (size_t)(bb*64+j)*1536 + hh*64 + d;
    Ks[j][d] = qkv[base + 512];
    Vs[j][d] = qkv[base + 1024];
  }
  for(int e=tid;e<1024;e+=256){
    int i=e>>6, d=e&63;
    Qs[i][d] = qkv[(size_t)(bb*64+qt*16+i)*1536 + hh*64 + d];
  }
  __syncthreads();
  int lane = tid&63, w = tid>>6;
  #pragma unroll
  for(int e=0;e<4;e++){
    int i = w + e*4, j = lane;
    int qi = qt*16 + i;
    float s2 = 0;
    #pragma unroll
    for(int d=0; d<64; d++) s2 += Qs[i][d]*Ks[j][d];
    float sval = (j<=qi) ? s2*0.125f : -1e9f;
    float mx = sval;
    #pragma unroll
    for(int off=32;off;off>>=1) mx = fmaxf(mx, __shfl_xor(mx,off));
    float ex = expf(sval - mx);
    float sm = ex;
    #pragma unroll
    for(int off=32;off;off>>=1) sm += __shfl_xor(sm,off);
    float p = ex/sm;
    Ps[i][j] = p;
    ap[(size_t)((bb*8+hh)*64 + qi)*64 + j] = p;
  }
  __syncthreads();
  #pragma unroll
  for(int e=0;e<4;e++){
    int i = w + e*4, d = lane;
    float acc = 0;
    #pragma unroll
    for(int j=0;j<64;j++) acc += Ps[i][j]*Vs[j][d];
    o[(size_t)(bb*64+qt*16+i)*512 + hh*64 + d] = f2b(acc);
  }
}

// ============ attention backward q-side ============
__global__ __launch_bounds__(256) void k_attn_bwd_q(const float* __restrict__ qkv, const float* __restrict__ dob,
    const float* __restrict__ ap, float* __restrict__ dsb, unsigned short* __restrict__ dqkv)
{
  int qt = blockIdx.x, hh = blockIdx.y, bb = blockIdx.z;
  __shared__ float Ks[64][65], Vs[64][65], DOs[16][65], Ss[16][64], Aps[16][64];
  int tid = threadIdx.x;
  for(int e=tid;e<4096;e+=256){
    int j=e>>6, d=e&63;
    size_t base = (size_t)(bb*64+j)*1536 + hh*64 + d;
    Ks[j][d] = qkv[base + 512];
    Vs[j][d] = qkv[base + 1024];
  }
  for(int e=tid;e<1024;e+=256){
    int i=e>>6, d=e&63;
    DOs[i][d] = dob[(size_t)(bb*64+qt*16+i)*512 + hh*64 + d];
    Aps[i][d] = ap[(size_t)((bb*8+hh)*64 + qt*16+i)*64 + d];
  }
  __syncthreads();
  int lane = tid&63, w = tid>>6;
  #pragma unroll
  for(int e=0;e<4;e++){
    int i = w + e*4, j = lane;
    float da = 0;
    #pragma unroll
    for(int d=0;d<64;d++) da += DOs[i][d]*Vs[j][d];
    float a = Aps[i][j];
    float r = da*a;
    #pragma unroll
    for(int off=32;off;off>>=1) r += __shfl_xor(r,off);
    float ds = a*(da - r)*0.125f;
    Ss[i][j] = ds;
    dsb[(size_t)((bb*8+hh)*64 + qt*16+i)*64 + j] = ds;
  }
  __syncthreads();
  #pragma unroll
  for(int e=0;e<4;e++){
    int i = w + e*4, d = lane;
    float acc = 0;
    #pragma unroll
    for(int j=0;j<64;j++) acc += Ss[i][j]*Ks[j][d];
    dqkv[(size_t)(bb*64+qt*16+i)*1536 + hh*64 + d] = f2b(acc);
  }
}

// ============ attention backward kv-side ============
__global__ __launch_bounds__(256) void k_attn_bwd_kv(const float* __restrict__ qkv, const float* __restrict__ dob,
    const float* __restrict__ ap, const float* __restrict__ dsb, unsigned short* __restrict__ dqkv)
{
  int kt = blockIdx.x, hh = blockIdx.y, bb = blockIdx.z;
  __shared__ float Qs[64][65], DOs[64][65], DSt[64][17], At[64][17];
  int tid = threadIdx.x;
  for(int e=tid;e<4096;e+=256){
    int i=e>>6, d=e&63;
    Qs[i][d]  = qkv[(size_t)(bb*64+i)*1536 + hh*64 + d];
    DOs[i][d] = dob[(size_t)(bb*64+i)*512 + hh*64 + d];
  }
  for(int e=tid;e<1024;e+=256){
    int i=e>>4, jj=e&15;
    size_t idx = (size_t)((bb*8+hh)*64 + i)*64 + kt*16 + jj;
    DSt[i][jj] = dsb[idx];
    At[i][jj]  = ap[idx];
  }
  __syncthreads();
  int lane = tid&63, w = tid>>6;
  #pragma unroll
  for(int e=0;e<4;e++){
    int jj = w + e*4, d = lane;
    float dk = 0, dv = 0;
    #pragma unroll
    for(int i2=0;i2<64;i2++){
      dk += DSt[i2][jj]*Qs[i2][d];
      dv += At[i2][jj]*DOs[i2][d];
    }
    size_t row = (size_t)(bb*64 + kt*16 + jj)*1536 + hh*64 + d;
    dqkv[row + 512]  = f2b(dk);
    dqkv[row + 1024] = f2b(dv);
  }
}

// ============ CE stats ============
__global__ __launch_bounds__(256) void k_ce_stats(const float* __restrict__ out,
    float* __restrict__ rowm, float* __restrict__ rowiz, int chunk)
{
  int n = blockIdx.x, tid = threadIdx.x;
  int R = (n>>6)*256 + chunk*64 + (n&63);
  const float* row = out + (size_t)R*32000;
  __shared__ float red[256];
  float mx = -3.4e38f;
  for(int v=tid; v<32000; v+=256) mx = fmaxf(mx, row[v]);
  red[tid] = mx; __syncthreads();
  for(int o=128;o;o>>=1){ if(tid<o) red[tid]=fmaxf(red[tid],red[tid+o]); __syncthreads(); }
  float m = red[0]; __syncthreads();
  float s = 0;
  for(int v=tid; v<32000; v+=256) s += expf(row[v]-m);
  red[tid] = s; __syncthreads();
  for(int o=128;o;o>>=1){ if(tid<o) red[tid]+=red[tid+o]; __syncthreads(); }
  if(tid==0){ rowm[n]=m; rowiz[n]=1.f/red[0]; }
}

// ============ dlogits (softmax - onehot)/256 -> bf16 ============
__global__ __launch_bounds__(256) void k_dlog(const float* __restrict__ out, const int* __restrict__ x,
    const float* __restrict__ rowm, const float* __restrict__ rowiz,
    unsigned short* __restrict__ dlog, int chunk)
{
  int n = blockIdx.x, tid = threadIdx.x;
  int b = n>>6, t = n&63;
  int R = b*256 + chunk*64 + t;
  int tgt = x[b*257 + chunk*64 + t + 1];
  float m = rowm[n], iz = rowiz[n]*(1.f/256.f);
  const float* row = out + (size_t)R*32000;
  unsigned short* dr = dlog + (size_t)n*32000;
  for(int v=tid; v<32000; v+=256){
    float a = expf(row[v]-m)*iz;
    if(v==tgt) a -= (1.f/256.f);
    dr[v] = f2b(a);
  }
}

__global__ __launch_bounds__(256) void k_reduce20(const float* __restrict__ p, float* __restrict__ o){
  int i = blockIdx.x*256 + threadIdx.x;
  float s = 0;
  #pragma unroll
  for(int z=0;z<20;z++) s += p[(size_t)z*131072 + i];
  o[i] = s;
}

// ============ elementwise ============
__global__ __launch_bounds__(256) void k_gelu_bwd(float* __restrict__ dg, const float* __restrict__ z,
    unsigned short* __restrict__ dzb){
  int i = blockIdx.x*256 + threadIdx.x;
  float v = dg[i]*gelu_df(z[i]);
  dg[i] = v;
  dzb[i] = f2b(v);
}

__global__ __launch_bounds__(256) void k_colsum_sgd(const float* __restrict__ X, float* __restrict__ bv, int N){
  int c = blockIdx.x*256 + threadIdx.x;
  if(c < N){
    float s = 0;
    for(int n=0;n<256;n++) s += X[(size_t)n*N + c];
    bv[c] -= LRATE*s;
  }
}

extern "C" void kernel_launch(void* const* d_in, const int* in_sizes, int n_in,
                              void* d_out, int out_size, void* d_ws, size_t ws_size,
                              hipStream_t stream)
{
  const int*   x      = (const int*)d_in[0];
  const float* embed  = (const float*)d_in[1];
  const float* pos    = (const float*)d_in[2];
  const float* ln1_g  = (const float*)d_in[3];
  const float* ln1_b  = (const float*)d_in[4];
  const float* qkv_w  = (const float*)d_in[5];
  const float* qkv_b  = (const float*)d_in[6];
  const float* proj_w = (const float*)d_in[7];
  const float* proj_b = (const float*)d_in[8];
  const float* ln2_g  = (const float*)d_in[9];
  const float* ln2_b  = (const float*)d_in[10];
  const float* mlp_w1 = (const float*)d_in[11];
  const float* mlp_b1 = (const float*)d_in[12];
  const float* mlp_w2 = (const float*)d_in[13];
  const float* mlp_b2 = (const float*)d_in[14];
  const float* lnf_g  = (const float*)d_in[15];
  const float* lnf_b  = (const float*)d_in[16];
  const float* head_w = (const float*)d_in[17];
  const float* head_b = (const float*)d_in[18];
  float* out = (float*)d_out;

  char* base = (char*)d_ws;
  size_t off = 0;
  auto AB = [&](size_t bytes)->char*{ char* p = base + off; off += (bytes + 255) & ~(size_t)255; return p; };
  // fp32
  float* W1c  = (float*)AB(16777216);
  float* W2c  = (float*)AB(16777216);
  float* B1c  = (float*)AB(32768);
  float* B2c  = (float*)AB(8192);
  float* hin  = (float*)AB(5*524288);
  float* h1s  = (float*)AB(4*524288);
  float* qkvs = (float*)AB(4*1572864);
  float* aps  = (float*)AB(4*524288);
  float* z1s  = (float*)AB(4*2097152);
  float* dg1  = (float*)AB(2097152);
  float* dhA  = (float*)AB(524288);
  float* dhB  = (float*)AB(524288);
  float* dxn  = (float*)AB(524288);
  float* dob  = (float*)AB(524288);
  float* dhfb = (float*)AB(524288);
  float* dsb  = (float*)AB(524288);
  float* dpart= (float*)AB(20*524288);
  float* ln1m = (float*)AB(4096); float* ln1r = (float*)AB(4096);
  float* ln2m = (float*)AB(4096); float* ln2r = (float*)AB(4096);
  float* lnfm = (float*)AB(1024); float* lnfr = (float*)AB(1024);
  float* rowm = (float*)AB(1024); float* rowiz= (float*)AB(1024);
  // bf16
  unsigned short* qkvwB = (unsigned short*)AB(6291456);
  unsigned short* projwB= (unsigned short*)AB(2097152);
  unsigned short* headwB= (unsigned short*)AB(32768000);
  unsigned short* W1b   = (unsigned short*)AB(8388608);
  unsigned short* W2b   = (unsigned short*)AB(8388608);
  unsigned short* z1gs  = (unsigned short*)AB(4194304);
  unsigned short* xn2bs = (unsigned short*)AB(1048576);
  unsigned short* xn1b  = (unsigned short*)AB(262144);
  unsigned short* hfbB  = (unsigned short*)AB(262144);
  unsigned short* obufB = (unsigned short*)AB(262144);
  unsigned short* dlogB = (unsigned short*)AB(16384000);
  unsigned short* dhAb  = (unsigned short*)AB(262144);
  unsigned short* dhBb  = (unsigned short*)AB(262144);
  unsigned short* dz1b  = (unsigned short*)AB(1048576);
  unsigned short* dqkvB = (unsigned short*)AB(786432);

  // ---- weight conversions (every call; deterministic) ----
  k_cvt<<<3072,256,0,stream>>>(qkv_w, qkvwB, 3145728);
  k_cvt<<<1024,256,0,stream>>>(proj_w, projwB, 1048576);
  k_cvt<<<16000,256,0,stream>>>(head_w, headwB, 16384000);
  k_cvt_dual<<<4096,256,0,stream>>>(mlp_w1, W1c, W1b, 4194304);
  k_cvt_dual<<<4096,256,0,stream>>>(mlp_w2, W2c, W2b, 4194304);
  hipMemcpyAsync(B1c, mlp_b1, 8192*sizeof(float), hipMemcpyDeviceToDevice, stream);
  hipMemcpyAsync(B2c, mlp_b2, 2048*sizeof(float), hipMemcpyDeviceToDevice, stream);

  for(int c=0;c<4;c++){
    // ---------------- forward ----------------
    k_embed<<<256,256,0,stream>>>(x, embed, pos, hin, c);
    for(int i=0;i<4;i++){
      float* h0 = hin + (size_t)i*131072;
      float* h2 = hin + (size_t)(i+1)*131072;
      float* h1 = h1s + (size_t)i*131072;
      float* qk = qkvs + (size_t)i*393216;
      float* ap = aps + (size_t)i*131072;
      float* z1 = z1s + (size_t)i*524288;
      unsigned short* xn2b = xn2bs + (size_t)i*131072;
      unsigned short* z1g  = z1gs + (size_t)i*524288;
      k_ln_fwd<<<256,256,0,stream>>>(h0, ln1_g+i*512, ln1_b+i*512, xn1b, ln1m+i*256, ln1r+i*256);
      k_mm<0,0,0><<<dim3(24,4,1),256,0,stream>>>(xn1b, qkvwB+(size_t)i*786432, qkv_b+i*1536, nullptr,
          qk, nullptr, nullptr, nullptr, 256,1536,512, 16, 0, -1);
      k_attn_fwd<<<dim3(4,8,4),256,0,stream>>>(qk, obufB, ap);
      k_mm<0,0,0><<<dim3(8,4,1),256,0,stream>>>(obufB, projwB+(size_t)i*262144, proj_b+i*512, h0,
          h1, nullptr, nullptr, nullptr, 256,512,512, 16, 0, -1);
      k_ln_fwd<<<256,256,0,stream>>>(h1, ln2_g+i*512, ln2_b+i*512, xn2b, ln2m+i*256, ln2r+i*256);
      k_mm<0,0,0><<<dim3(32,4,1),256,0,stream>>>(xn2b, W1b+(size_t)i*1048576, B1c+i*2048, nullptr,
          z1, z1g, nullptr, nullptr, 256,2048,512, 16, 1, -1);
      k_mm<0,0,0><<<dim3(8,4,1),256,0,stream>>>(z1g, W2b+(size_t)i*1048576, B2c+i*512, h1,
          h2, nullptr, nullptr, nullptr, 256,512,2048, 64, 0, -1);
    }
    k_ln_fwd<<<256,256,0,stream>>>(hin+4*131072, lnf_g, lnf_b, hfbB, lnfm, lnfr);
    k_mm<0,0,0><<<dim3(500,4,1),256,0,stream>>>(hfbB, headwB, head_b, nullptr,
        out, nullptr, nullptr, nullptr, 256,32000,512, 16, 0, c);

    // ---------------- backward ----------------
    k_ce_stats<<<256,256,0,stream>>>(out, rowm, rowiz, c);
    k_dlog<<<256,256,0,stream>>>(out, x, rowm, rowiz, dlogB, c);
    k_mm<0,1,0><<<dim3(8,4,20),256,0,stream>>>(dlogB, headwB, nullptr, nullptr,
        dpart, nullptr, nullptr, nullptr, 256,512,32000, 50, 0, -1);
    k_reduce20<<<512,256,0,stream>>>(dpart, dhfb);
    k_ln_bwd<<<256,256,0,stream>>>(dhfb, hin+4*131072, lnf_g, lnfm, lnfr, nullptr, dhA, dhAb);
    for(int i=3;i>=0;i--){
      float* h0 = hin + (size_t)i*131072;
      float* h1 = h1s + (size_t)i*131072;
      float* qk = qkvs + (size_t)i*393216;
      float* ap = aps + (size_t)i*131072;
      float* z1 = z1s + (size_t)i*524288;
      unsigned short* xn2b = xn2bs + (size_t)i*131072;
      unsigned short* z1g  = z1gs + (size_t)i*524288;
      // MLP backward (dhA/dhAb = dh2)
      k_mm<0,1,0><<<dim3(32,4,1),256,0,stream>>>(dhAb, W2b+(size_t)i*1048576, nullptr, nullptr,
          dg1, nullptr, nullptr, nullptr, 256,2048,512, 16, 0, -1);            // dg1 (reads W2b)
      k_colsum_sgd<<<2,256,0,stream>>>(dhA, B2c+i*512, 512);
      k_mm<1,0,1><<<dim3(8,32,1),256,0,stream>>>(z1g, dhAb, nullptr, nullptr,
          nullptr, nullptr, W2c+(size_t)i*1048576, W2b+(size_t)i*1048576, 2048,512,256, 8, 0, -1); // W2 sgd
      k_gelu_bwd<<<2048,256,0,stream>>>(dg1, z1, dz1b);
      k_mm<0,1,0><<<dim3(8,4,1),256,0,stream>>>(dz1b, W1b+(size_t)i*1048576, nullptr, nullptr,
          dxn, nullptr, nullptr, nullptr, 256,512,2048, 64, 0, -1);            // dxn2 (reads W1b)
      k_colsum_sgd<<<8,256,0,stream>>>(dg1, B1c+i*2048, 2048);
      k_mm<1,0,1><<<dim3(32,8,1),256,0,stream>>>(xn2b, dz1b, nullptr, nullptr,
          nullptr, nullptr, W1c+(size_t)i*1048576, W1b+(size_t)i*1048576, 512,2048,256, 8, 0, -1); // W1 sgd
      k_ln_bwd<<<256,256,0,stream>>>(dxn, h1, ln2_g+i*512, ln2m+i*256, ln2r+i*256, dhA, dhB, dhBb);
      // attention backward
      k_mm<0,1,0><<<dim3(8,4,1),256,0,stream>>>(dhBb, projwB+(size_t)i*262144, nullptr, nullptr,
          dob, nullptr, nullptr, nullptr, 256,512,512, 16, 0, -1);             // do
      k_attn_bwd_q<<<dim3(4,8,4),256,0,stream>>>(qk, dob, ap, dsb, dqkvB);
      k_attn_bwd_kv<<<dim3(4,8,4),256,0,stream>>>(qk, dob, ap, dsb, dqkvB);
      k_mm<0,1,0><<<dim3(8,4,1),256,0,stream>>>(dqkvB, qkvwB+(size_t)i*786432, nullptr, nullptr,
          dxn, nullptr, nullptr, nullptr, 256,512,1536, 48, 0, -1);            // dxn1
      k_ln_bwd<<<256,256,0,stream>>>(dxn, h0, ln1_g+i*512, ln1m+i*256, ln1r+i*256, dhB, dhA, dhAb);
    }
  }
}

// Round 3
// 4425.209 us; speedup vs baseline: 3.6796x; 1.1254x over previous
//
#include <hip/hip_runtime.h>
#include <cstddef>

#define LRATE 3e-4f

typedef short short8 __attribute__((ext_vector_type(8)));
typedef float f32x4 __attribute__((ext_vector_type(4)));
typedef __bf16 bf16x8 __attribute__((ext_vector_type(8)));

__device__ __forceinline__ unsigned short f2b(float f){
  unsigned u = __builtin_bit_cast(unsigned, f);
  unsigned r = (u + 0x7fffu + ((u>>16)&1u)) >> 16;
  return (unsigned short)r;
}
__device__ __forceinline__ float b2f(unsigned short s){
  unsigned u = ((unsigned)s)<<16;
  return __builtin_bit_cast(float, u);
}
__device__ __forceinline__ float gelu_f(float x){
  float u = 0.7978845608028654f*(x + 0.044715f*x*x*x);
  float t = tanhf(u);
  return 0.5f*x*(1.f+t);
}
__device__ __forceinline__ float gelu_df(float x){
  float x2 = x*x;
  float u = 0.7978845608028654f*(x + 0.044715f*x*x2);
  float t = tanhf(u);
  return 0.5f*(1.f+t) + 0.5f*x*(1.f-t*t)*0.7978845608028654f*(1.f+0.134145f*x2);
}
__device__ __forceinline__ void gll16(const void* g, void* l){
  __builtin_amdgcn_global_load_lds(
      (const __attribute__((address_space(1))) unsigned int*)(g),
      (__attribute__((address_space(3))) unsigned int*)(l), 16, 0, 0);
}

// ============ universal NT bf16 MFMA GEMM ============
// C[M,N] = A[M,K] @ B[N,K]^T.  A,B row-major bf16, K-contiguous rows, K%64==0.
// global_load_lds staging, swizzle-via-source, BK=64, 2-barrier loop.
// Epilogue: +bias, +resid, *gelu_df(zsrc) [fused gelu-bwd], split-K z offset,
// head row remap, fp32 out and/or bf16 out (optionally gelu-fwd'd).
template<int TILE>
__global__ __launch_bounds__(256) void k_nt(
    const unsigned short* __restrict__ Ag, const unsigned short* __restrict__ Bg,
    const float* __restrict__ bias, const float* __restrict__ resid,
    const float* __restrict__ zsrc,
    float* __restrict__ outf, unsigned short* __restrict__ outb,
    int M, int N, int K, int k_iters, int gelu_b, int remap_c)
{
  constexpr int F = TILE/32;            // 16x16 frags per wave dim
  __shared__ short Asm[TILE*64];
  __shared__ short Bsm[TILE*64];
  int tid = threadIdx.x, lane = tid&63, w = tid>>6;
  int wr = w>>1, wc = w&1, r16 = lane&15, kg = lane>>4;
  int bn = blockIdx.x*TILE, bm = blockIdx.y*TILE;
  int k0 = blockIdx.z * k_iters * 64;
  f32x4 acc[F][F] = {};
  const size_t Ks = K;

  for(int it=0; it<k_iters; ++it, k0+=64){
    #pragma unroll
    for(int q=0;q<TILE/32;q++){
      int id = w*(TILE*2) + q*64 + lane;
      int row = id>>3, s = id&7, gc = s^(row&7);
      gll16(Ag + (size_t)(bm+row)*Ks + k0 + gc*8, (char*)Asm + (w*(TILE*2)+q*64)*16);
    }
    #pragma unroll
    for(int q=0;q<TILE/32;q++){
      int id = w*(TILE*2) + q*64 + lane;
      int row = id>>3, s = id&7, gc = s^(row&7);
      gll16(Bg + (size_t)(bn+row)*Ks + k0 + gc*8, (char*)Bsm + (w*(TILE*2)+q*64)*16);
    }
    __syncthreads();
    #pragma unroll
    for(int h=0; h<2; h++){
      bf16x8 af[F], bfr[F];
      #pragma unroll
      for(int fa=0; fa<F; fa++){
        int row = wr*(TILE/2) + fa*16 + r16;
        int c = (h*4 + kg) ^ (row&7);
        af[fa] = __builtin_bit_cast(bf16x8, *(const short8*)((const char*)Asm + row*128 + c*16));
      }
      #pragma unroll
      for(int fb=0; fb<F; fb++){
        int row = wc*(TILE/2) + fb*16 + r16;
        int c = (h*4 + kg) ^ (row&7);
        bfr[fb] = __builtin_bit_cast(bf16x8, *(const short8*)((const char*)Bsm + row*128 + c*16));
      }
      #pragma unroll
      for(int fa=0; fa<F; fa++)
        #pragma unroll
        for(int fb=0; fb<F; fb++)
          acc[fa][fb] = __builtin_amdgcn_mfma_f32_16x16x32_bf16(af[fa], bfr[fb], acc[fa][fb], 0,0,0);
    }
    __syncthreads();
  }

  int rb = lane>>4;
  #pragma unroll
  for(int fa=0; fa<F; fa++){
    #pragma unroll
    for(int fb=0; fb<F; fb++){
      f32x4 av = acc[fa][fb];
      #pragma unroll
      for(int i=0;i<4;i++){
        int m = bm + wr*(TILE/2) + fa*16 + rb*4 + i;
        int n = bn + wc*(TILE/2) + fb*16 + r16;
        float v = av[i];
        if(bias) v += bias[n];
        if(resid) v += resid[(size_t)m*N + n];
        if(zsrc) v *= gelu_df(zsrc[(size_t)m*N + n]);
        int mo = (remap_c>=0)? ((m>>6)*256 + remap_c*64 + (m&63)) : m;
        if(outf) outf[(size_t)blockIdx.z*M*N + (size_t)mo*N + n] = v;
        if(outb) outb[(size_t)mo*N + n] = f2b(gelu_b ? gelu_f(v) : v);
      }
    }
  }
}

// ============ TN wgrad + SGD: W[M,N] -= LR*(A^T@B); A[256,M], B[256,N] bf16 ============
// updates fp32 master Wf, bf16 copy Wb, and bf16 transposed copy Wt[N,M]
__global__ __launch_bounds__(256) void k_tn_sgd(
    const unsigned short* __restrict__ Ag, const unsigned short* __restrict__ Bg,
    float* __restrict__ Wf, unsigned short* __restrict__ Wb, unsigned short* __restrict__ Wt,
    int M, int N)
{
  __shared__ short Asm[64*40];
  __shared__ short Bsm[64*40];
  __shared__ short Tsm[64*72];
  int tid = threadIdx.x;
  int bm = blockIdx.y*64, bn = blockIdx.x*64;
  f32x4 acc00={},acc01={},acc10={},acc11={};
  int lane = tid&63, w = tid>>6, wr = w>>1, wc = w&1;
  int r16 = lane&15, kg = lane>>4;
  for(int k0=0; k0<256; k0+=32){
    { int kk = tid>>3, ms=(tid&7)*8;
      short8 v = *(const short8*)(Ag + (size_t)(k0+kk)*M + bm + ms);
      #pragma unroll
      for(int j=0;j<8;j++){ int row=ms+j; Asm[row*40 + (((kk>>3)^((row>>3)&3))<<3) + (kk&7)] = v[j]; } }
    { int kk = tid>>3, ns=(tid&7)*8;
      short8 v = *(const short8*)(Bg + (size_t)(k0+kk)*N + bn + ns);
      #pragma unroll
      for(int j=0;j<8;j++){ int row=ns+j; Bsm[row*40 + (((kk>>3)^((row>>3)&3))<<3) + (kk&7)] = v[j]; } }
    __syncthreads();
    int ra0 = wr*32 + r16, ra1 = ra0+16, rb0 = wc*32 + r16, rb1 = rb0+16;
    bf16x8 a0 = __builtin_bit_cast(bf16x8, *(const short8*)(Asm + ra0*40 + ((kg ^ ((ra0>>3)&3))<<3)));
    bf16x8 a1 = __builtin_bit_cast(bf16x8, *(const short8*)(Asm + ra1*40 + ((kg ^ ((ra1>>3)&3))<<3)));
    bf16x8 b0 = __builtin_bit_cast(bf16x8, *(const short8*)(Bsm + rb0*40 + ((kg ^ ((rb0>>3)&3))<<3)));
    bf16x8 b1 = __builtin_bit_cast(bf16x8, *(const short8*)(Bsm + rb1*40 + ((kg ^ ((rb1>>3)&3))<<3)));
    acc00 = __builtin_amdgcn_mfma_f32_16x16x32_bf16(a0, b0, acc00, 0,0,0);
    acc01 = __builtin_amdgcn_mfma_f32_16x16x32_bf16(a0, b1, acc01, 0,0,0);
    acc10 = __builtin_amdgcn_mfma_f32_16x16x32_bf16(a1, b0, acc10, 0,0,0);
    acc11 = __builtin_amdgcn_mfma_f32_16x16x32_bf16(a1, b1, acc11, 0,0,0);
    __syncthreads();
  }
  int rb = lane>>4;
  #pragma unroll
  for(int ar=0;ar<2;ar++){
    #pragma unroll
    for(int bc=0;bc<2;bc++){
      f32x4 av = (ar==0) ? (bc==0?acc00:acc01) : (bc==0?acc10:acc11);
      #pragma unroll
      for(int i=0;i<4;i++){
        int lm = wr*32 + ar*16 + rb*4 + i;
        int ln = wc*32 + bc*16 + r16;
        size_t oi = (size_t)(bm+lm)*N + bn+ln;
        float wv = Wf[oi] - LRATE*av[i];
        Wf[oi] = wv;
        unsigned short ub = f2b(wv);
        Wb[oi] = ub;
        Tsm[ln*72 + lm] = (short)ub;
      }
    }
  }
  __syncthreads();
  #pragma unroll
  for(int q=0;q<2;q++){
    int id = tid*2+q;
    int ln = id>>3, ch = id&7;
    short8 vv = *(const short8*)(Tsm + ln*72 + ch*8);
    *(short8*)(Wt + (size_t)(bn+ln)*M + bm + ch*8) = vv;
  }
}

// ============ transpose-convert: src fp32 [R,C] (z layers) -> dstT bf16 [C,R], opt dstO bf16 [R,C], opt dstF fp32 ============
__global__ __launch_bounds__(256) void k_cvt_t(const float* __restrict__ src,
    unsigned short* __restrict__ dstT, unsigned short* __restrict__ dstO, float* __restrict__ dstF,
    int R, int C)
{
  __shared__ short T[64*72];
  size_t zoff = (size_t)blockIdx.z * R * C;
  int c0 = blockIdx.x*64, r0 = blockIdx.y*64;
  int tid = threadIdx.x;
  #pragma unroll
  for(int q=0;q<16;q++){
    int e = tid + q*256;
    int r = e>>6, cc = e&63;
    float v = src[zoff + (size_t)(r0+r)*C + c0+cc];
    unsigned short bv = f2b(v);
    T[cc*72 + r] = (short)bv;
    if(dstO) dstO[zoff + (size_t)(r0+r)*C + c0+cc] = bv;
    if(dstF) dstF[zoff + (size_t)(r0+r)*C + c0+cc] = v;
  }
  __syncthreads();
  #pragma unroll
  for(int q=0;q<2;q++){
    int id = tid*2+q;
    int cc = id>>3, ch = id&7;
    short8 vv = *(const short8*)(T + cc*72 + ch*8);
    *(short8*)(dstT + zoff + (size_t)(c0+cc)*R + r0 + ch*8) = vv;
  }
}

// ============ embed + pos ============
__global__ __launch_bounds__(256) void k_embed(const int* __restrict__ x, const float* __restrict__ emb,
    const float* __restrict__ pos, float* __restrict__ h, int chunk)
{
  int n = blockIdx.x, tid = threadIdx.x;
  int b = n>>6, t = n&63;
  int tok = x[b*257 + chunk*64 + t];
  size_t b0 = (size_t)n*512 + tid;
  h[b0]     = emb[(size_t)tok*512 + tid]       + pos[t*512 + tid];
  h[b0+256] = emb[(size_t)tok*512 + tid + 256] + pos[t*512 + tid + 256];
}

// ============ LayerNorm fwd -> bf16 ============
__global__ __launch_bounds__(256) void k_ln_fwd(const float* __restrict__ x, const float* __restrict__ g,
    const float* __restrict__ b, unsigned short* __restrict__ yb, float* __restrict__ mean, float* __restrict__ rstd)
{
  int n = blockIdx.x, tid = threadIdx.x;
  size_t b0 = (size_t)n*512 + tid;
  float x0 = x[b0], x1 = x[b0+256];
  __shared__ float red[256];
  red[tid] = x0 + x1; __syncthreads();
  for(int o=128;o;o>>=1){ if(tid<o) red[tid]+=red[tid+o]; __syncthreads(); }
  float m = red[0]*(1.f/512.f); __syncthreads();
  float d0 = x0-m, d1 = x1-m;
  red[tid] = d0*d0 + d1*d1; __syncthreads();
  for(int o=128;o;o>>=1){ if(tid<o) red[tid]+=red[tid+o]; __syncthreads(); }
  float r = rsqrtf(red[0]*(1.f/512.f) + 1e-5f);
  if(tid==0){ mean[n]=m; rstd[n]=r; }
  yb[b0]     = f2b(d0*r*g[tid]     + b[tid]);
  yb[b0+256] = f2b(d1*r*g[tid+256] + b[tid+256]);
}

// ============ LayerNorm bwd ============
__global__ __launch_bounds__(256) void k_ln_bwd(const float* __restrict__ dy, const float* __restrict__ x,
    const float* __restrict__ g, const float* __restrict__ mean, const float* __restrict__ rstd,
    const float* __restrict__ addin, float* __restrict__ dx, unsigned short* __restrict__ dxb)
{
  int n = blockIdx.x, tid = threadIdx.x;
  float m = mean[n], r = rstd[n];
  size_t b0 = (size_t)n*512 + tid;
  float x0 = x[b0], x1 = x[b0+256];
  float xh0 = (x0-m)*r, xh1 = (x1-m)*r;
  float gh0 = dy[b0]*g[tid], gh1 = dy[b0+256]*g[tid+256];
  __shared__ float r1[256], r2[256];
  r1[tid] = gh0+gh1; r2[tid] = gh0*xh0 + gh1*xh1;
  __syncthreads();
  for(int o=128;o;o>>=1){ if(tid<o){ r1[tid]+=r1[tid+o]; r2[tid]+=r2[tid+o]; } __syncthreads(); }
  float mg = r1[0]*(1.f/512.f), mgx = r2[0]*(1.f/512.f);
  float d0 = (gh0 - mg - xh0*mgx)*r;
  float d1 = (gh1 - mg - xh1*mgx)*r;
  if(addin){ d0 += addin[b0]; d1 += addin[b0+256]; }
  dx[b0] = d0; dx[b0+256] = d1;
  dxb[b0] = f2b(d0); dxb[b0+256] = f2b(d1);
}

// ============ attention forward ============
__global__ __launch_bounds__(256) void k_attn_fwd(const float* __restrict__ qkv, unsigned short* __restrict__ o,
    float* __restrict__ ap)
{
  int qt = blockIdx.x, hh = blockIdx.y, bb = blockIdx.z;
  __shared__ float Ks[64][65], Vs[64][65], Qs[16][65], Ps[16][64];
  int tid = threadIdx.x;
  for(int e=tid;e<4096;e+=256){
    int j=e>>6, d=e&63;
    size_t base = (size_t)(bb*64+j)*1536 + hh*64 + d;
    Ks[j][d] = qkv[base + 512];
    Vs[j][d] = qkv[base + 1024];
  }
  for(int e=tid;e<1024;e+=256){
    int i=e>>6, d=e&63;
    Qs[i][d] = qkv[(size_t)(bb*64+qt*16+i)*1536 + hh*64 + d];
  }
  __syncthreads();
  int lane = tid&63, w = tid>>6;
  #pragma unroll
  for(int e=0;e<4;e++){
    int i = w + e*4, j = lane;
    int qi = qt*16 + i;
    float s2 = 0;
    #pragma unroll
    for(int d=0; d<64; d++) s2 += Qs[i][d]*Ks[j][d];
    float sval = (j<=qi) ? s2*0.125f : -1e9f;
    float mx = sval;
    #pragma unroll
    for(int off=32;off;off>>=1) mx = fmaxf(mx, __shfl_xor(mx,off));
    float ex = expf(sval - mx);
    float sm = ex;
    #pragma unroll
    for(int off=32;off;off>>=1) sm += __shfl_xor(sm,off);
    float p = ex/sm;
    Ps[i][j] = p;
    ap[(size_t)((bb*8+hh)*64 + qi)*64 + j] = p;
  }
  __syncthreads();
  #pragma unroll
  for(int e=0;e<4;e++){
    int i = w + e*4, d = lane;
    float acc = 0;
    #pragma unroll
    for(int j=0;j<64;j++) acc += Ps[i][j]*Vs[j][d];
    o[(size_t)(bb*64+qt*16+i)*512 + hh*64 + d] = f2b(acc);
  }
}

// ============ attention backward q-side ============
__global__ __launch_bounds__(256) void k_attn_bwd_q(const float* __restrict__ qkv, const float* __restrict__ dob,
    const float* __restrict__ ap, float* __restrict__ dsb, unsigned short* __restrict__ dqkv)
{
  int qt = blockIdx.x, hh = blockIdx.y, bb = blockIdx.z;
  __shared__ float Ks[64][65], Vs[64][65], DOs[16][65], Ss[16][64], Aps[16][64];
  int tid = threadIdx.x;
  for(int e=tid;e<4096;e+=256){
    int j=e>>6, d=e&63;
    size_t base = (size_t)(bb*64+j)*1536 + hh*64 + d;
    Ks[j][d] = qkv[base + 512];
    Vs[j][d] = qkv[base + 1024];
  }
  for(int e=tid;e<1024;e+=256){
    int i=e>>6, d=e&63;
    DOs[i][d] = dob[(size_t)(bb*64+qt*16+i)*512 + hh*64 + d];
    Aps[i][d] = ap[(size_t)((bb*8+hh)*64 + qt*16+i)*64 + d];
  }
  __syncthreads();
  int lane = tid&63, w = tid>>6;
  #pragma unroll
  for(int e=0;e<4;e++){
    int i = w + e*4, j = lane;
    float da = 0;
    #pragma unroll
    for(int d=0;d<64;d++) da += DOs[i][d]*Vs[j][d];
    float a = Aps[i][j];
    float r = da*a;
    #pragma unroll
    for(int off=32;off;off>>=1) r += __shfl_xor(r,off);
    float ds = a*(da - r)*0.125f;
    Ss[i][j] = ds;
    dsb[(size_t)((bb*8+hh)*64 + qt*16+i)*64 + j] = ds;
  }
  __syncthreads();
  #pragma unroll
  for(int e=0;e<4;e++){
    int i = w + e*4, d = lane;
    float acc = 0;
    #pragma unroll
    for(int j=0;j<64;j++) acc += Ss[i][j]*Ks[j][d];
    dqkv[(size_t)(bb*64+qt*16+i)*1536 + hh*64 + d] = f2b(acc);
  }
}

// ============ attention backward kv-side ============
__global__ __launch_bounds__(256) void k_attn_bwd_kv(const float* __restrict__ qkv, const float* __restrict__ dob,
    const float* __restrict__ ap, const float* __restrict__ dsb, unsigned short* __restrict__ dqkv)
{
  int kt = blockIdx.x, hh = blockIdx.y, bb = blockIdx.z;
  __shared__ float Qs[64][65], DOs[64][65], DSt[64][17], At[64][17];
  int tid = threadIdx.x;
  for(int e=tid;e<4096;e+=256){
    int i=e>>6, d=e&63;
    Qs[i][d]  = qkv[(size_t)(bb*64+i)*1536 + hh*64 + d];
    DOs[i][d] = dob[(size_t)(bb*64+i)*512 + hh*64 + d];
  }
  for(int e=tid;e<1024;e+=256){
    int i=e>>4, jj=e&15;
    size_t idx = (size_t)((bb*8+hh)*64 + i)*64 + kt*16 + jj;
    DSt[i][jj] = dsb[idx];
    At[i][jj]  = ap[idx];
  }
  __syncthreads();
  int lane = tid&63, w = tid>>6;
  #pragma unroll
  for(int e=0;e<4;e++){
    int jj = w + e*4, d = lane;
    float dk = 0, dv = 0;
    #pragma unroll
    for(int i2=0;i2<64;i2++){
      dk += DSt[i2][jj]*Qs[i2][d];
      dv += At[i2][jj]*DOs[i2][d];
    }
    size_t row = (size_t)(bb*64 + kt*16 + jj)*1536 + hh*64 + d;
    dqkv[row + 512]  = f2b(dk);
    dqkv[row + 1024] = f2b(dv);
  }
}

// ============ fused CE stats + dlogits -> bf16 ============
__global__ __launch_bounds__(256) void k_ce_dlog(const float* __restrict__ out, const int* __restrict__ x,
    unsigned short* __restrict__ dlog, int chunk)
{
  __shared__ unsigned short eb[32000];
  __shared__ float red[256];
  int n = blockIdx.x, tid = threadIdx.x;
  int b = n>>6, t = n&63;
  int R = b*256 + chunk*64 + t;
  int tgt = x[b*257 + chunk*64 + t + 1];
  const float* row = out + (size_t)R*32000;
  float mx = -3.4e38f;
  for(int v=tid; v<32000; v+=256) mx = fmaxf(mx, row[v]);
  red[tid]=mx; __syncthreads();
  for(int o=128;o;o>>=1){ if(tid<o) red[tid]=fmaxf(red[tid],red[tid+o]); __syncthreads(); }
  float m = red[0]; __syncthreads();
  float s=0;
  for(int v=tid; v<32000; v+=256){ float e = expf(row[v]-m); s+=e; eb[v]=f2b(e); }
  red[tid]=s; __syncthreads();
  for(int o=128;o;o>>=1){ if(tid<o) red[tid]+=red[tid+o]; __syncthreads(); }
  float iz = 1.f/red[0] * (1.f/256.f);
  unsigned short* dr = dlog + (size_t)n*32000;
  for(int v=tid; v<32000; v+=256){
    float a = b2f(eb[v])*iz;
    if(v==tgt) a -= (1.f/256.f);
    dr[v] = f2b(a);
  }
}

__global__ __launch_bounds__(256) void k_reduce25(const float* __restrict__ p, float* __restrict__ o){
  int i = blockIdx.x*256 + threadIdx.x;
  float s = 0;
  #pragma unroll
  for(int z=0;z<25;z++) s += p[(size_t)z*131072 + i];
  o[i] = s;
}

__global__ __launch_bounds__(256) void k_colsum_sgd(const float* __restrict__ X, float* __restrict__ bv, int N){
  int c = blockIdx.x*256 + threadIdx.x;
  if(c < N){
    float s = 0;
    for(int n=0;n<256;n++) s += X[(size_t)n*N + c];
    bv[c] -= LRATE*s;
  }
}

extern "C" void kernel_launch(void* const* d_in, const int* in_sizes, int n_in,
                              void* d_out, int out_size, void* d_ws, size_t ws_size,
                              hipStream_t stream)
{
  const int*   x      = (const int*)d_in[0];
  const float* embed  = (const float*)d_in[1];
  const float* pos    = (const float*)d_in[2];
  const float* ln1_g  = (const float*)d_in[3];
  const float* ln1_b  = (const float*)d_in[4];
  const float* qkv_w  = (const float*)d_in[5];
  const float* qkv_b  = (const float*)d_in[6];
  const float* proj_w = (const float*)d_in[7];
  const float* proj_b = (const float*)d_in[8];
  const float* ln2_g  = (const float*)d_in[9];
  const float* ln2_b  = (const float*)d_in[10];
  const float* mlp_w1 = (const float*)d_in[11];
  const float* mlp_b1 = (const float*)d_in[12];
  const float* mlp_w2 = (const float*)d_in[13];
  const float* mlp_b2 = (const float*)d_in[14];
  const float* lnf_g  = (const float*)d_in[15];
  const float* lnf_b  = (const float*)d_in[16];
  const float* head_w = (const float*)d_in[17];
  const float* head_b = (const float*)d_in[18];
  float* out = (float*)d_out;

  char* base = (char*)d_ws;
  size_t off = 0;
  auto AB = [&](size_t bytes)->char*{ char* p = base + off; off += (bytes + 255) & ~(size_t)255; return p; };
  // fp32
  float* W1c  = (float*)AB(16777216);
  float* W2c  = (float*)AB(16777216);
  float* B1c  = (float*)AB(32768);
  float* B2c  = (float*)AB(8192);
  float* hin  = (float*)AB(5*524288);
  float* h1s  = (float*)AB(4*524288);
  float* qkvs = (float*)AB(4*1572864);
  float* aps  = (float*)AB(4*524288);
  float* z1s  = (float*)AB(4*2097152);
  float* dg1f = (float*)AB(2097152);
  float* dhA  = (float*)AB(524288);
  float* dhB  = (float*)AB(524288);
  float* dxn  = (float*)AB(524288);
  float* dob  = (float*)AB(524288);
  float* dhfb = (float*)AB(524288);
  float* dsb  = (float*)AB(524288);
  float* dpart= (float*)AB(25*524288);
  float* ln1m = (float*)AB(4096); float* ln1r = (float*)AB(4096);
  float* ln2m = (float*)AB(4096); float* ln2r = (float*)AB(4096);
  float* lnfm = (float*)AB(1024); float* lnfr = (float*)AB(1024);
  // bf16
  unsigned short* qkvwB = (unsigned short*)AB(6291456);
  unsigned short* qkvwT = (unsigned short*)AB(6291456);
  unsigned short* projwB= (unsigned short*)AB(2097152);
  unsigned short* projwT= (unsigned short*)AB(2097152);
  unsigned short* headwB= (unsigned short*)AB(32768000);
  unsigned short* headwT= (unsigned short*)AB(32768000);
  unsigned short* W1b   = (unsigned short*)AB(8388608);
  unsigned short* W1t   = (unsigned short*)AB(8388608);
  unsigned short* W2b   = (unsigned short*)AB(8388608);
  unsigned short* W2t   = (unsigned short*)AB(8388608);
  unsigned short* z1gs  = (unsigned short*)AB(4194304);
  unsigned short* xn2bs = (unsigned short*)AB(1048576);
  unsigned short* xn1b  = (unsigned short*)AB(262144);
  unsigned short* hfbB  = (unsigned short*)AB(262144);
  unsigned short* obufB = (unsigned short*)AB(262144);
  unsigned short* dlogB = (unsigned short*)AB(16384000);
  unsigned short* dhAb  = (unsigned short*)AB(262144);
  unsigned short* dhBb  = (unsigned short*)AB(262144);
  unsigned short* dz1b  = (unsigned short*)AB(1048576);
  unsigned short* dqkvB = (unsigned short*)AB(786432);

  // ---- weight conversions + transposes (both layouts) ----
  k_cvt_t<<<dim3(24,8,4),256,0,stream>>>(qkv_w, qkvwT, qkvwB, nullptr, 512, 1536);
  k_cvt_t<<<dim3(8,8,4),256,0,stream>>>(proj_w, projwT, projwB, nullptr, 512, 512);
  k_cvt_t<<<dim3(500,8,1),256,0,stream>>>(head_w, headwT, headwB, nullptr, 512, 32000);
  k_cvt_t<<<dim3(32,8,4),256,0,stream>>>(mlp_w1, W1t, W1b, W1c, 512, 2048);
  k_cvt_t<<<dim3(8,32,4),256,0,stream>>>(mlp_w2, W2t, W2b, W2c, 2048, 512);
  hipMemcpyAsync(B1c, mlp_b1, 8192*sizeof(float), hipMemcpyDeviceToDevice, stream);
  hipMemcpyAsync(B2c, mlp_b2, 2048*sizeof(float), hipMemcpyDeviceToDevice, stream);

  for(int c=0;c<4;c++){
    // ---------------- forward ----------------
    k_embed<<<256,256,0,stream>>>(x, embed, pos, hin, c);
    for(int i=0;i<4;i++){
      float* h0 = hin + (size_t)i*131072;
      float* h2 = hin + (size_t)(i+1)*131072;
      float* h1 = h1s + (size_t)i*131072;
      float* qk = qkvs + (size_t)i*393216;
      float* ap = aps + (size_t)i*131072;
      float* z1 = z1s + (size_t)i*524288;
      unsigned short* xn2b = xn2bs + (size_t)i*131072;
      unsigned short* z1g  = z1gs + (size_t)i*524288;
      k_ln_fwd<<<256,256,0,stream>>>(h0, ln1_g+i*512, ln1_b+i*512, xn1b, ln1m+i*256, ln1r+i*256);
      k_nt<64><<<dim3(24,4),256,0,stream>>>(xn1b, qkvwT+(size_t)i*786432, qkv_b+i*1536, nullptr, nullptr,
          qk, nullptr, 256,1536,512, 8, 0, -1);
      k_attn_fwd<<<dim3(4,8,4),256,0,stream>>>(qk, obufB, ap);
      k_nt<64><<<dim3(8,4),256,0,stream>>>(obufB, projwT+(size_t)i*262144, proj_b+i*512, h0, nullptr,
          h1, nullptr, 256,512,512, 8, 0, -1);
      k_ln_fwd<<<256,256,0,stream>>>(h1, ln2_g+i*512, ln2_b+i*512, xn2b, ln2m+i*256, ln2r+i*256);
      k_nt<64><<<dim3(32,4),256,0,stream>>>(xn2b, W1t+(size_t)i*1048576, B1c+i*2048, nullptr, nullptr,
          z1, z1g, 256,2048,512, 8, 1, -1);
      k_nt<64><<<dim3(8,4),256,0,stream>>>(z1g, W2t+(size_t)i*1048576, B2c+i*512, h1, nullptr,
          h2, nullptr, 256,512,2048, 32, 0, -1);
    }
    k_ln_fwd<<<256,256,0,stream>>>(hin+4*131072, lnf_g, lnf_b, hfbB, lnfm, lnfr);
    k_nt<128><<<dim3(250,2),256,0,stream>>>(hfbB, headwT, head_b, nullptr, nullptr,
        out, nullptr, 256,32000,512, 8, 0, c);

    // ---------------- backward ----------------
    k_ce_dlog<<<256,256,0,stream>>>(out, x, dlogB, c);
    k_nt<128><<<dim3(4,2,25),256,0,stream>>>(dlogB, headwB, nullptr, nullptr, nullptr,
        dpart, nullptr, 256,512,32000, 20, 0, -1);
    k_reduce25<<<512,256,0,stream>>>(dpart, dhfb);
    k_ln_bwd<<<256,256,0,stream>>>(dhfb, hin+4*131072, lnf_g, lnfm, lnfr, nullptr, dhA, dhAb);
    for(int i=3;i>=0;i--){
      float* h0 = hin + (size_t)i*131072;
      float* h1 = h1s + (size_t)i*131072;
      float* qk = qkvs + (size_t)i*393216;
      float* ap = aps + (size_t)i*131072;
      float* z1 = z1s + (size_t)i*524288;
      unsigned short* xn2b = xn2bs + (size_t)i*131072;
      unsigned short* z1g  = z1gs + (size_t)i*524288;
      // MLP backward: dg1 = (dh2 @ W2^T) * gelu_df(z1)  [fused]
      k_nt<64><<<dim3(32,4),256,0,stream>>>(dhAb, W2b+(size_t)i*1048576, nullptr, nullptr, z1,
          dg1f, dz1b, 256,2048,512, 8, 0, -1);
      k_colsum_sgd<<<2,256,0,stream>>>(dhA, B2c+i*512, 512);
      k_tn_sgd<<<dim3(8,32),256,0,stream>>>(z1g, dhAb,
          W2c+(size_t)i*1048576, W2b+(size_t)i*1048576, W2t+(size_t)i*1048576, 2048, 512);
      k_nt<64><<<dim3(8,4),256,0,stream>>>(dz1b, W1b+(size_t)i*1048576, nullptr, nullptr, nullptr,
          dxn, nullptr, 256,512,2048, 32, 0, -1);
      k_colsum_sgd<<<8,256,0,stream>>>(dg1f, B1c+i*2048, 2048);
      k_tn_sgd<<<dim3(32,8),256,0,stream>>>(xn2b, dz1b,
          W1c+(size_t)i*1048576, W1b+(size_t)i*1048576, W1t+(size_t)i*1048576, 512, 2048);
      k_ln_bwd<<<256,256,0,stream>>>(dxn, h1, ln2_g+i*512, ln2m+i*256, ln2r+i*256, dhA, dhB, dhBb);
      // attention backward
      k_nt<64><<<dim3(8,4),256,0,stream>>>(dhBb, projwB+(size_t)i*262144, nullptr, nullptr, nullptr,
          dob, nullptr, 256,512,512, 8, 0, -1);
      k_attn_bwd_q<<<dim3(4,8,4),256,0,stream>>>(qk, dob, ap, dsb, dqkvB);
      k_attn_bwd_kv<<<dim3(4,8,4),256,0,stream>>>(qk, dob, ap, dsb, dqkvB);
      k_nt<64><<<dim3(8,4),256,0,stream>>>(dqkvB, qkvwB+(size_t)i*786432, nullptr, nullptr, nullptr,
          dxn, nullptr, 256,512,1536, 24, 0, -1);
      k_ln_bwd<<<256,256,0,stream>>>(dxn, h0, ln1_g+i*512, ln1m+i*256, ln1r+i*256, dhB, dhA, dhAb);
    }
  }
}